// Round 1
// baseline (282.431 us; speedup 1.0000x reference)
//
#include <hip/hip_runtime.h>

#define B     64
#define CIN   3
#define COUT  16
#define H     256
#define W     256
#define HO    255            // conv out spatial
#define WO    255
#define HF    254            // window out spatial
#define WF    254
#define NPIX  (B * HO * WO)  // 4,161,600
#define NOUT  (B * HF * WF)  // 4,129,024
#define BN_EPS 1e-5f

// ---------------- kernel 1: per-channel sum / sumsq of conv+bias ----------------
__global__ __launch_bounds__(256) void k_stats(const float* __restrict__ x,
                                               const float* __restrict__ w,
                                               const float* __restrict__ bias,
                                               float* __restrict__ acc) {
    __shared__ float ws_w[COUT * CIN * 4];
    __shared__ float ws_b[COUT];
    int tid = threadIdx.x;
    if (tid < COUT * CIN * 4) ws_w[tid] = w[tid];
    if (tid < COUT) ws_b[tid] = bias[tid];
    __syncthreads();

    float s[COUT], q[COUT];
#pragma unroll
    for (int c = 0; c < COUT; c++) { s[c] = 0.f; q[c] = 0.f; }

    int stride = gridDim.x * blockDim.x;
    for (int p = blockIdx.x * blockDim.x + tid; p < NPIX; p += stride) {
        int b = p / (HO * WO);
        int r = p % (HO * WO);
        int i = r / WO, j = r % WO;
        const float* xb = x + (long)b * (CIN * H * W) + i * W + j;
        float xv[CIN][4];
#pragma unroll
        for (int ic = 0; ic < CIN; ic++) {
            const float* xp = xb + ic * (H * W);
            xv[ic][0] = xp[0];     xv[ic][1] = xp[1];
            xv[ic][2] = xp[W];     xv[ic][3] = xp[W + 1];
        }
#pragma unroll
        for (int c = 0; c < COUT; c++) {
            float f = ws_b[c];
#pragma unroll
            for (int ic = 0; ic < CIN; ic++) {
                const float* wp = ws_w + (c * CIN + ic) * 4;
                f = fmaf(wp[0], xv[ic][0], f);
                f = fmaf(wp[1], xv[ic][1], f);
                f = fmaf(wp[2], xv[ic][2], f);
                f = fmaf(wp[3], xv[ic][3], f);
            }
            s[c] += f;
            q[c] = fmaf(f, f, q[c]);
        }
    }

    // wave64 reduce
#pragma unroll
    for (int c = 0; c < COUT; c++) {
        for (int off = 32; off; off >>= 1) {
            s[c] += __shfl_down(s[c], off, 64);
            q[c] += __shfl_down(q[c], off, 64);
        }
    }
    __shared__ float red[4][2 * COUT];
    int wave = tid >> 6, lane = tid & 63;
    if (lane == 0) {
#pragma unroll
        for (int c = 0; c < COUT; c++) {
            red[wave][c] = s[c];
            red[wave][COUT + c] = q[c];
        }
    }
    __syncthreads();
    if (tid < 2 * COUT) {
        float v = red[0][tid] + red[1][tid] + red[2][tid] + red[3][tid];
        atomicAdd(&acc[tid], v);
    }
}

// ---------------- kernel 2: finalize scale/shift ----------------
__global__ void k_final(const float* __restrict__ acc,
                        const float* __restrict__ gamma,
                        const float* __restrict__ beta,
                        float* __restrict__ sc) {
    int c = threadIdx.x;
    if (c < COUT) {
        const float n = (float)NPIX;
        float mu  = acc[c] / n;
        float var = acc[COUT + c] / n - mu * mu;
        float rs  = rsqrtf(var + BN_EPS);
        float scale = gamma[c] * rs;
        sc[c]        = scale;
        sc[COUT + c] = beta[c] - mu * scale;
    }
}

// ---------------- kernel 3: channel-summed tanh(relu(bn(conv))) ----------------
__global__ __launch_bounds__(256) void k_csum(const float* __restrict__ x,
                                              const float* __restrict__ w,
                                              const float* __restrict__ bias,
                                              const float* __restrict__ sc,
                                              float* __restrict__ sarr) {
    __shared__ float ws_w[COUT * CIN * 4];
    __shared__ float ws_b[COUT], ws_s[COUT], ws_h[COUT];
    int tid = threadIdx.x;
    if (tid < COUT * CIN * 4) ws_w[tid] = w[tid];
    if (tid < COUT) {
        ws_b[tid] = bias[tid];
        ws_s[tid] = sc[tid];
        ws_h[tid] = sc[COUT + tid];
    }
    __syncthreads();

    int p = blockIdx.x * blockDim.x + tid;
    if (p >= NPIX) return;
    int b = p / (HO * WO);
    int r = p % (HO * WO);
    int i = r / WO, j = r % WO;
    const float* xb = x + (long)b * (CIN * H * W) + i * W + j;
    float xv[CIN][4];
#pragma unroll
    for (int ic = 0; ic < CIN; ic++) {
        const float* xp = xb + ic * (H * W);
        xv[ic][0] = xp[0];     xv[ic][1] = xp[1];
        xv[ic][2] = xp[W];     xv[ic][3] = xp[W + 1];
    }
    float sum = 0.f;
#pragma unroll
    for (int c = 0; c < COUT; c++) {
        float f = ws_b[c];
#pragma unroll
        for (int ic = 0; ic < CIN; ic++) {
            const float* wp = ws_w + (c * CIN + ic) * 4;
            f = fmaf(wp[0], xv[ic][0], f);
            f = fmaf(wp[1], xv[ic][1], f);
            f = fmaf(wp[2], xv[ic][2], f);
            f = fmaf(wp[3], xv[ic][3], f);
        }
        float a = fmaf(ws_s[c], f, ws_h[c]);
        a = fmaxf(a, 0.f);                       // relu
        float t = 1.f - 2.f / (__expf(2.f * a) + 1.f);  // tanh, a >= 0
        sum += t;
    }
    sarr[p] = sum;
}

// ---------------- kernel 4: 2x2 window mean over pre-channel-summed s ----------------
__global__ __launch_bounds__(256) void k_win(const float* __restrict__ sarr,
                                             float* __restrict__ out) {
    int p = blockIdx.x * blockDim.x + threadIdx.x;
    if (p >= NOUT) return;
    int b = p / (HF * WF);
    int r = p % (HF * WF);
    int i = r / WF, j = r % WF;
    const float* sp = sarr + ((long)b * HO + i) * WO + j;
    out[p] = (sp[0] + sp[1] + sp[WO] + sp[WO + 1]) * (1.f / (COUT * 4));
}

extern "C" void kernel_launch(void* const* d_in, const int* in_sizes, int n_in,
                              void* d_out, int out_size, void* d_ws, size_t ws_size,
                              hipStream_t stream) {
    const float* x     = (const float*)d_in[0];
    const float* w     = (const float*)d_in[1];
    const float* bias  = (const float*)d_in[2];
    const float* gamma = (const float*)d_in[3];
    const float* beta  = (const float*)d_in[4];
    float* out = (float*)d_out;

    float* acc  = (float*)d_ws;   // 32 floats: sum[16], sumsq[16]
    float* sc   = acc + 32;       // 32 floats: scale[16], shift[16]
    float* sarr = acc + 64;       // NPIX floats

    hipMemsetAsync(d_ws, 0, 32 * sizeof(float), stream);

    k_stats<<<2048, 256, 0, stream>>>(x, w, bias, acc);
    k_final<<<1, 64, 0, stream>>>(acc, gamma, beta, sc);
    k_csum<<<(NPIX + 255) / 256, 256, 0, stream>>>(x, w, bias, sc, sarr);
    k_win<<<(NOUT + 255) / 256, 256, 0, stream>>>(sarr, out);
}

// Round 2
// 184.778 us; speedup vs baseline: 1.5285x; 1.5285x over previous
//
#include <hip/hip_runtime.h>

#define B     64
#define CIN   3
#define COUT  16
#define H     256
#define W     256
#define HO    255            // conv out spatial
#define WO    255
#define HF    254            // window out spatial
#define WF    254
#define NPIX  (B * HO * WO)  // 4,161,600
#define NOUT  (B * HF * WF)  // 4,129,024
#define BN_EPS 1e-5f

#define SEGS  32                   // 8-pixel segments per conv row (32*8 >= 255)
#define NITEM (B * HO * SEGS)      // 522,240 work items
#define SROW  256                  // padded sarr row stride (col 255 = pad)

#define SB    510                  // k_stats blocks
#define ST    256
#define SITER 4                    // items per thread in k_stats (510*256*4 = NITEM)

__device__ __forceinline__ float4 ld4(const float* p) { return *(const float4*)p; }

// Load packed per-channel params into LDS: [c][0..11]=w, [12]=bias, [13]=scale, [14]=shift
__device__ __forceinline__ void load_wpk(float* wpk, const float* w, const float* bias,
                                         const float* sc, int tid) {
    int c = tid >> 4, k = tid & 15;
    float v = 0.f;
    if (k < 12)       v = w[c * 12 + k];
    else if (k == 12) v = bias[c];
    else if (k == 13) v = sc ? sc[c] : 0.f;
    else if (k == 14) v = sc ? sc[COUT + c] : 0.f;
    wpk[tid] = v;
}

// Load the 2 x 9 x 3ch input patch for an 8-pixel segment. off8 clamps the
// 9th column load in-bounds for the tail segment (its value is masked/padded).
__device__ __forceinline__ void load_patch(const float* xp, int off8,
                                           float x0[CIN][9], float x1[CIN][9]) {
#pragma unroll
    for (int ic = 0; ic < CIN; ic++) {
        const float* p0 = xp + ic * (H * W);
        const float* p1 = p0 + W;
        float4 a = ld4(p0), b = ld4(p0 + 4);
        x0[ic][0] = a.x; x0[ic][1] = a.y; x0[ic][2] = a.z; x0[ic][3] = a.w;
        x0[ic][4] = b.x; x0[ic][5] = b.y; x0[ic][6] = b.z; x0[ic][7] = b.w;
        x0[ic][8] = p0[off8];
        float4 c4 = ld4(p1), d = ld4(p1 + 4);
        x1[ic][0] = c4.x; x1[ic][1] = c4.y; x1[ic][2] = c4.z; x1[ic][3] = c4.w;
        x1[ic][4] = d.x;  x1[ic][5] = d.y;  x1[ic][6] = d.z;  x1[ic][7] = d.w;
        x1[ic][8] = p1[off8];
    }
}

#define CONV_F(u)                                                  \
    float f = wd.x;                                                \
    f = fmaf(wa.x, x0[0][u], f); f = fmaf(wa.y, x0[0][(u)+1], f);  \
    f = fmaf(wa.z, x1[0][u], f); f = fmaf(wa.w, x1[0][(u)+1], f);  \
    f = fmaf(wb.x, x0[1][u], f); f = fmaf(wb.y, x0[1][(u)+1], f);  \
    f = fmaf(wb.z, x1[1][u], f); f = fmaf(wb.w, x1[1][(u)+1], f);  \
    f = fmaf(wc4.x, x0[2][u], f); f = fmaf(wc4.y, x0[2][(u)+1], f);\
    f = fmaf(wc4.z, x1[2][u], f); f = fmaf(wc4.w, x1[2][(u)+1], f);

// ---------------- kernel 1: per-channel sum / sumsq of conv+bias ----------------
__global__ __launch_bounds__(256) void k_stats(const float* __restrict__ x,
                                               const float* __restrict__ w,
                                               const float* __restrict__ bias,
                                               float* __restrict__ acc) {
    __shared__ float wpk[COUT * 16];
    int tid = threadIdx.x;
    load_wpk(wpk, w, bias, nullptr, tid);
    __syncthreads();

    float s[COUT], q[COUT];
#pragma unroll
    for (int c = 0; c < COUT; c++) { s[c] = 0.f; q[c] = 0.f; }

    int gtid = blockIdx.x * ST + tid;
    for (int it = 0; it < SITER; it++) {
        int item = gtid + it * (SB * ST);
        int jseg = item & (SEGS - 1);
        int row  = item >> 5;                 // b*HO + i
        int bb   = row / HO;
        int i    = row - bb * HO;
        int j0   = jseg << 3;
        const float* xp = x + (size_t)bb * (CIN * H * W) + i * W + j0;
        float m7  = (jseg == SEGS - 1) ? 0.f : 1.f;
        int   off8 = (jseg == SEGS - 1) ? 7 : 8;

        float x0[CIN][9], x1[CIN][9];
        load_patch(xp, off8, x0, x1);

#pragma unroll
        for (int c = 0; c < COUT; c++) {
            const float4* wv = (const float4*)(wpk + (c << 4));
            float4 wa = wv[0], wb = wv[1], wc4 = wv[2], wd = wv[3];
#pragma unroll
            for (int u = 0; u < 8; u++) {
                CONV_F(u)
                if (u == 7) f *= m7;          // mask tail pixel of last segment
                s[c] += f;
                q[c] = fmaf(f, f, q[c]);
            }
        }
    }

    // wave64 butterfly reduce, then cross-wave via LDS, then 32 atomics
#pragma unroll
    for (int c = 0; c < COUT; c++) {
        for (int off = 32; off; off >>= 1) {
            s[c] += __shfl_down(s[c], off, 64);
            q[c] += __shfl_down(q[c], off, 64);
        }
    }
    __shared__ float red[4][2 * COUT];
    int wave = tid >> 6, lane = tid & 63;
    if (lane == 0) {
#pragma unroll
        for (int c = 0; c < COUT; c++) {
            red[wave][c] = s[c];
            red[wave][COUT + c] = q[c];
        }
    }
    __syncthreads();
    if (tid < 2 * COUT) {
        float v = red[0][tid] + red[1][tid] + red[2][tid] + red[3][tid];
        atomicAdd(&acc[tid], v);
    }
}

// ---------------- kernel 2: finalize scale/shift ----------------
__global__ void k_final(const float* __restrict__ acc,
                        const float* __restrict__ gamma,
                        const float* __restrict__ beta,
                        float* __restrict__ sc) {
    int c = threadIdx.x;
    if (c < COUT) {
        const float n = (float)NPIX;
        float mu  = acc[c] / n;
        float var = acc[COUT + c] / n - mu * mu;
        float rs  = rsqrtf(var + BN_EPS);
        float scale = gamma[c] * rs;
        sc[c]        = scale;
        sc[COUT + c] = beta[c] - mu * scale;
    }
}

// ---------------- kernel 3: channel-summed tanh(relu(bn(conv))) ----------------
__global__ __launch_bounds__(256) void k_csum(const float* __restrict__ x,
                                              const float* __restrict__ w,
                                              const float* __restrict__ bias,
                                              const float* __restrict__ sc,
                                              float* __restrict__ sarr) {
    __shared__ float wpk[COUT * 16];
    int tid = threadIdx.x;
    load_wpk(wpk, w, bias, sc, tid);
    __syncthreads();

    int item = blockIdx.x * 256 + tid;        // 2040 blocks * 256 == NITEM
    int jseg = item & (SEGS - 1);
    int row  = item >> 5;                     // b*HO + i
    int bb   = row / HO;
    int i    = row - bb * HO;
    int j0   = jseg << 3;
    const float* xp = x + (size_t)bb * (CIN * H * W) + i * W + j0;
    int off8 = (jseg == SEGS - 1) ? 7 : 8;

    float x0[CIN][9], x1[CIN][9];
    load_patch(xp, off8, x0, x1);

    float sum[8];
#pragma unroll
    for (int u = 0; u < 8; u++) sum[u] = 0.f;

#pragma unroll
    for (int c = 0; c < COUT; c++) {
        const float4* wv = (const float4*)(wpk + (c << 4));
        float4 wa = wv[0], wb = wv[1], wc4 = wv[2], wd = wv[3];
#pragma unroll
        for (int u = 0; u < 8; u++) {
            CONV_F(u)
            float a = fmaf(wd.y, f, wd.z);            // scale*f + shift
            a = fmaxf(a, 0.f);                        // relu
            float t = 1.f - 2.f / (__expf(2.f * a) + 1.f);  // tanh, a >= 0
            sum[u] += t;
        }
    }
    // padded row stride: tail lane's 8th value lands in pad col 255, never read
    float* sp = sarr + (size_t)row * SROW + j0;
    *(float4*)sp       = make_float4(sum[0], sum[1], sum[2], sum[3]);
    *(float4*)(sp + 4) = make_float4(sum[4], sum[5], sum[6], sum[7]);
}

// ---------------- kernel 4: 2x2 window mean over pre-channel-summed s ----------------
__global__ __launch_bounds__(256) void k_win(const float* __restrict__ sarr,
                                             float* __restrict__ out) {
    int p = blockIdx.x * blockDim.x + threadIdx.x;
    if (p >= NOUT) return;
    int b = p / (HF * WF);
    int r = p % (HF * WF);
    int i = r / WF, j = r % WF;
    const float* sp = sarr + ((size_t)(b * HO + i)) * SROW + j;
    out[p] = (sp[0] + sp[1] + sp[SROW] + sp[SROW + 1]) * (1.f / (COUT * 4));
}

extern "C" void kernel_launch(void* const* d_in, const int* in_sizes, int n_in,
                              void* d_out, int out_size, void* d_ws, size_t ws_size,
                              hipStream_t stream) {
    const float* x     = (const float*)d_in[0];
    const float* w     = (const float*)d_in[1];
    const float* bias  = (const float*)d_in[2];
    const float* gamma = (const float*)d_in[3];
    const float* beta  = (const float*)d_in[4];
    float* out = (float*)d_out;

    float* acc  = (float*)d_ws;     // 32 floats: sum[16], sumsq[16]
    float* sc   = acc + 32;         // 32 floats: scale[16], shift[16]
    float* sarr = acc + 256;        // B*HO*SROW floats (padded rows), 1KB-aligned

    hipMemsetAsync(d_ws, 0, 32 * sizeof(float), stream);

    k_stats<<<SB, ST, 0, stream>>>(x, w, bias, acc);
    k_final<<<1, 64, 0, stream>>>(acc, gamma, beta, sc);
    k_csum<<<NITEM / 256, 256, 0, stream>>>(x, w, bias, sc, sarr);
    k_win<<<(NOUT + 255) / 256, 256, 0, stream>>>(sarr, out);
}

// Round 3
// 159.623 us; speedup vs baseline: 1.7694x; 1.1576x over previous
//
#include <hip/hip_runtime.h>

#define B     64
#define CIN   3
#define COUT  16
#define H     256
#define W     256
#define HO    255            // conv out spatial
#define WO    255
#define HF    254            // window out spatial
#define WF    254
#define NPIX  (B * HO * WO)  // 4,161,600
#define BN_EPS 1e-5f

#define SEGS  32                   // 8-pixel segments per conv row
#define NITEM (B * HO * SEGS)      // 522,240 segment items
#define SB    255                  // k_stats blocks
#define ST    256
#define SITER 8                    // 255*256*8 == NITEM

#define NS 12                      // shifted-x sums
#define NM 78                      // upper-tri cross-moments
#define NA 90

#define RB    7                    // output rows per fused block (8 s-rows -> 256 tasks, balanced)
#define RBLKS 37                   // ceil(HF/RB)
#define LSTRIDE 260                // LDS s-tile row stride (260 % 32 == 4 -> conflict-free reads)

__device__ __forceinline__ float4 ld4(const float* p) { return *(const float4*)p; }

// M index for pair (k,l), l>=k
#define MIDX(k, l) (12*(k) - ((k)*((k)-1))/2 + ((l)-(k)))

// Load the 2 x 9 x 3ch input patch for an 8-pixel segment. off8 clamps the
// 9th column in-bounds for the tail segment (its value is masked/unused).
__device__ __forceinline__ void load_patch(const float* xp, int off8,
                                           float x0[CIN][9], float x1[CIN][9]) {
#pragma unroll
    for (int ic = 0; ic < CIN; ic++) {
        const float* p0 = xp + ic * (H * W);
        const float* p1 = p0 + W;
        float4 a = ld4(p0), b = ld4(p0 + 4);
        x0[ic][0] = a.x; x0[ic][1] = a.y; x0[ic][2] = a.z; x0[ic][3] = a.w;
        x0[ic][4] = b.x; x0[ic][5] = b.y; x0[ic][6] = b.z; x0[ic][7] = b.w;
        x0[ic][8] = p0[off8];
        float4 c4 = ld4(p1), d = ld4(p1 + 4);
        x1[ic][0] = c4.x; x1[ic][1] = c4.y; x1[ic][2] = c4.z; x1[ic][3] = c4.w;
        x1[ic][4] = d.x;  x1[ic][5] = d.y;  x1[ic][6] = d.z;  x1[ic][7] = d.w;
        x1[ic][8] = p1[off8];
    }
}

#define CONV_F(u)                                                  \
    float f = wd.x;                                                \
    f = fmaf(wa.x, x0[0][u], f); f = fmaf(wa.y, x0[0][(u)+1], f);  \
    f = fmaf(wa.z, x1[0][u], f); f = fmaf(wa.w, x1[0][(u)+1], f);  \
    f = fmaf(wb.x, x0[1][u], f); f = fmaf(wb.y, x0[1][(u)+1], f);  \
    f = fmaf(wb.z, x1[1][u], f); f = fmaf(wb.w, x1[1][(u)+1], f);  \
    f = fmaf(wc4.x, x0[2][u], f); f = fmaf(wc4.y, x0[2][(u)+1], f);\
    f = fmaf(wc4.z, x1[2][u], f); f = fmaf(wc4.w, x1[2][(u)+1], f);

// ---- kernel 1: channel-independent moments S_k = sum(v_k), M_kl = sum(v_k v_l) ----
__global__ __launch_bounds__(256) void k_stats(const float* __restrict__ x,
                                               float* __restrict__ acc) {
    float S[NS], M[NM];
#pragma unroll
    for (int k = 0; k < NS; k++) S[k] = 0.f;
#pragma unroll
    for (int k = 0; k < NM; k++) M[k] = 0.f;

    int tid  = threadIdx.x;
    int gtid = blockIdx.x * ST + tid;
#pragma unroll 1
    for (int it = 0; it < SITER; it++) {
        int item = gtid + it * (SB * ST);
        int jseg = item & (SEGS - 1);
        int row  = item >> 5;                 // b*HO + i
        int bb   = row / HO;
        int i    = row - bb * HO;
        int j0   = jseg << 3;
        const float* xp = x + (size_t)bb * (CIN * H * W) + i * W + j0;
        bool tail = (jseg == SEGS - 1);
        int  off8 = tail ? 7 : 8;

        float x0[CIN][9], x1[CIN][9];
        load_patch(xp, off8, x0, x1);

#pragma unroll
        for (int u = 0; u < 8; u++) {
            if (!(u == 7 && tail)) {          // skip invalid tail pixel (col 255)
                float v[NS];
#pragma unroll
                for (int ic = 0; ic < CIN; ic++) {
                    v[ic*4+0] = x0[ic][u];
                    v[ic*4+1] = x0[ic][u+1];
                    v[ic*4+2] = x1[ic][u];
                    v[ic*4+3] = x1[ic][u+1];
                }
#pragma unroll
                for (int k = 0; k < NS; k++) {
                    S[k] += v[k];
#pragma unroll
                    for (int l = k; l < NS; l++) {
                        M[MIDX(k,l)] = fmaf(v[k], v[l], M[MIDX(k,l)]);
                    }
                }
            }
        }
    }

    // wave64 butterfly reduce, cross-wave via LDS, 90 atomics per block
    int lane = tid & 63, wave = tid >> 6;
#pragma unroll
    for (int k = 0; k < NS; k++)
        for (int off = 32; off; off >>= 1) S[k] += __shfl_down(S[k], off, 64);
#pragma unroll
    for (int k = 0; k < NM; k++)
        for (int off = 32; off; off >>= 1) M[k] += __shfl_down(M[k], off, 64);

    __shared__ float red[4][NA];
    if (lane == 0) {
#pragma unroll
        for (int k = 0; k < NS; k++) red[wave][k] = S[k];
#pragma unroll
        for (int k = 0; k < NM; k++) red[wave][NS + k] = M[k];
    }
    __syncthreads();
    if (tid < NA) {
        float v = red[0][tid] + red[1][tid] + red[2][tid] + red[3][tid];
        atomicAdd(&acc[tid], v);
    }
}

// ---- kernel 2: per-channel BN affine from moments; fold 2*log2(e) for exp2-tanh ----
__global__ void k_final(const float* __restrict__ acc,
                        const float* __restrict__ w,
                        const float* __restrict__ bias,
                        const float* __restrict__ gamma,
                        const float* __restrict__ beta,
                        float* __restrict__ sc) {
    int c = threadIdx.x;
    if (c >= COUT) return;
    float wv[NS];
#pragma unroll
    for (int k = 0; k < NS; k++) wv[k] = w[c * NS + k];
    const float* S = acc;
    const float* M = acc + NS;
    float sw = 0.f, quad = 0.f;
#pragma unroll
    for (int k = 0; k < NS; k++) {
        sw = fmaf(wv[k], S[k], sw);
#pragma unroll
        for (int l = k; l < NS; l++) {
            float coef = (l == k) ? wv[k] * wv[k] : 2.f * wv[k] * wv[l];
            quad = fmaf(coef, M[MIDX(k,l)], quad);
        }
    }
    const float n = (float)NPIX;
    float b     = bias[c];
    float sumf  = fmaf(n, b, sw);
    float sumf2 = n * b * b + 2.f * b * sw + quad;
    float mu  = sumf / n;
    float var = sumf2 / n - mu * mu;
    float rs  = rsqrtf(var + BN_EPS);
    float scale = gamma[c] * rs;
    float shift = beta[c] - mu * scale;
    const float C2 = 2.8853900817779268f;   // 2*log2(e); relu(x)*c == relu(c*x), c>0
    sc[c]        = scale * C2;
    sc[COUT + c] = shift * C2;
}

// ---- kernel 3 (fused): s = sum_c tanh(relu(bn(conv))) into LDS tile, then 2x2 window mean ----
__global__ __launch_bounds__(256) void k_csum(const float* __restrict__ x,
                                              const float* __restrict__ w,
                                              const float* __restrict__ bias,
                                              const float* __restrict__ sc,
                                              float* __restrict__ out) {
    __shared__ float wpk[COUT * 16];
    __shared__ float sld[(RB + 1) * LSTRIDE];
    int tid = threadIdx.x;
    {   // packed per-channel params: [0..11]=w, [12]=bias, [13]=scale2, [14]=shift2
        int c = tid >> 4, k = tid & 15;
        float v = 0.f;
        if (k < 12)       v = w[c * 12 + k];
        else if (k == 12) v = bias[c];
        else if (k == 13) v = sc[c];
        else if (k == 14) v = sc[COUT + c];
        wpk[tid] = v;
    }
    int blk   = blockIdx.x;
    int bb    = blk / RBLKS;
    int rblk  = blk - bb * RBLKS;
    int rbase = rblk * RB;
    __syncthreads();

    // phase 1: one 8-pixel s-segment per thread (8 rows x 32 segs = 256 tasks)
    int sr = tid >> 5;               // 0..7
    int si = rbase + sr;
    int jseg = tid & 31;
    int j0 = jseg << 3;
    if (si < HO) {
        const float* xp = x + (size_t)bb * (CIN * H * W) + si * W + j0;
        int off8 = (jseg == 31) ? 7 : 8;
        float x0[CIN][9], x1[CIN][9];
        load_patch(xp, off8, x0, x1);

        float sum[8];
#pragma unroll
        for (int u = 0; u < 8; u++) sum[u] = 0.f;

#pragma unroll
        for (int c = 0; c < COUT; c++) {
            const float4* wv4 = (const float4*)(wpk + (c << 4));
            float4 wa = wv4[0], wb = wv4[1], wc4 = wv4[2], wd = wv4[3];
#pragma unroll
            for (int u = 0; u < 8; u++) {
                CONV_F(u)
                float a2 = fmaf(wd.y, f, wd.z);            // 2log2e*(scale*f+shift)
                a2 = fmaxf(a2, 0.f);                       // relu (scaled)
                float E = __builtin_amdgcn_exp2f(a2);      // e^{2a}
                float r = __builtin_amdgcn_rcpf(E + 1.f);
                sum[u] = fmaf(-2.f, r, sum[u] + 1.f);      // += 1 - 2/(e^{2a}+1)
            }
        }
        float* sp = &sld[sr * LSTRIDE + j0];
        *(float4*)sp       = make_float4(sum[0], sum[1], sum[2], sum[3]);
        *(float4*)(sp + 4) = make_float4(sum[4], sum[5], sum[6], sum[7]);
    }
    __syncthreads();

    // phase 2: 2x2 window means; thread -> (row tid>>5, cols (tid&31)+32u) for coalesced stores
    int orl = tid >> 5;              // 0..7, valid rows 0..RB-1
    int orow = rbase + orl;
    if (orl < RB && orow < HF) {
        const float* s0 = &sld[orl * LSTRIDE];
        const float* s1 = s0 + LSTRIDE;
        float* op = out + ((size_t)bb * HF + orow) * WF;
        int oc0 = tid & 31;
#pragma unroll
        for (int u = 0; u < 8; u++) {
            int c = oc0 + (u << 5);
            if (c < WF) {
                op[c] = (s0[c] + s0[c+1] + s1[c] + s1[c+1]) * (1.f / (COUT * 4));
            }
        }
    }
}

extern "C" void kernel_launch(void* const* d_in, const int* in_sizes, int n_in,
                              void* d_out, int out_size, void* d_ws, size_t ws_size,
                              hipStream_t stream) {
    const float* x     = (const float*)d_in[0];
    const float* w     = (const float*)d_in[1];
    const float* bias  = (const float*)d_in[2];
    const float* gamma = (const float*)d_in[3];
    const float* beta  = (const float*)d_in[4];
    float* out = (float*)d_out;

    float* acc = (float*)d_ws;      // 90 floats: S[12], M[78]
    float* sc  = acc + 128;         // 32 floats: scale2[16], shift2[16]

    hipMemsetAsync(d_ws, 0, 512, stream);

    k_stats<<<SB, ST, 0, stream>>>(x, acc);
    k_final<<<1, 64, 0, stream>>>(acc, w, bias, gamma, beta, sc);
    k_csum<<<B * RBLKS, 256, 0, stream>>>(x, w, bias, sc, out);
}